// Round 1
// baseline (329.480 us; speedup 1.0000x reference)
//
#include <hip/hip_runtime.h>

// Problem constants (from reference):
//   ROWS*COLUMNS = 8192*8192 = 67,108,864 elements
//   CENTROID_LEN = 4  -> 16,777,216 code groups
//   CODEBOOK_NUM = 2, CENTROIDS_NUM = 256 -> codebook table = 2048 floats (8 KB)
//   BLOCK_SIZE = 64 -> one scale per 16 code groups
//   codes flat layout (row-major reshape(-1)): first 8,388,608 entries use
//   codebook 0, the rest use codebook 1 (reference adds offset 256*cb).

#define N_GROUPS  16777216
#define HALF      8388608

__global__ __launch_bounds__(256) void dequant_kernel(
    const float* __restrict__ codebooks,   // [2*256*4] fp32
    const float* __restrict__ scales,      // [N_GROUPS/16] fp32
    const int*   __restrict__ codes,       // [N_GROUPS] int32, flat
    float*       __restrict__ out)         // [N_GROUPS*4] fp32
{
    const int i = blockIdx.x * blockDim.x + threadIdx.x;   // code-group index

    // Coalesced 4B code load
    const int code = codes[i];

    // Codebook select per flattened-codes layout
    const int cb_off = (i >= HALF) ? 256 : 0;

    // 16B gather from the 8 KB table (L1-resident)
    const float4 cent = ((const float4*)codebooks)[cb_off + code];

    // One scale per 64 output elems == per 16 code groups (wave-broadcast)
    const float s = scales[i >> 4];

    float4 o;
    o.x = cent.x * s;
    o.y = cent.y * s;
    o.z = cent.z * s;
    o.w = cent.w * s;

    // Coalesced 16B/lane store
    ((float4*)out)[i] = o;
}

extern "C" void kernel_launch(void* const* d_in, const int* in_sizes, int n_in,
                              void* d_out, int out_size, void* d_ws, size_t ws_size,
                              hipStream_t stream) {
    const float* codebooks = (const float*)d_in[0];
    const float* scales    = (const float*)d_in[1];
    const int*   codes     = (const int*)d_in[2];
    float*       out       = (float*)d_out;

    // N_GROUPS / 256 = 65536 blocks, exact coverage
    dequant_kernel<<<N_GROUPS / 256, 256, 0, stream>>>(codebooks, scales, codes, out);
}

// Round 3
// 322.481 us; speedup vs baseline: 1.0217x; 1.0217x over previous
//
#include <hip/hip_runtime.h>

// Dequantize: out[g*4..g*4+3] = codebook[cb(g)][codes[g]] * scales[g/16]
//   N_GROUPS = 16,777,216 (8192*8192/4); first half uses codebook 0, second half codebook 1.
//   Codebook: 2 x 256 x float4 (8 KB, 4 KB per half) -> staged in LDS per block.
//
// Block covers 2048 consecutive groups (256 thr x 8 groups/thr, stride-256
// interleave so every load/store instruction is a contiguous wave access).
// HALF (8,388,608) is a multiple of 2048, so the codebook half is block-uniform.

#define N_GROUPS  16777216
#define HALF      8388608
#define GPT       8
#define BLOCK     256
#define GROUPS_PER_BLOCK (BLOCK * GPT)   // 2048

typedef float f32x4 __attribute__((ext_vector_type(4)));  // native vector: OK for nontemporal builtins

__global__ __launch_bounds__(256) void dequant_kernel(
    const f32x4* __restrict__ codebooks,  // [2*256] float4
    const float* __restrict__ scales,     // [N_GROUPS/16]
    const int*   __restrict__ codes,      // [N_GROUPS]
    f32x4*       __restrict__ out)        // [N_GROUPS]
{
    __shared__ f32x4 lut[256];

    const int base = blockIdx.x * GROUPS_PER_BLOCK;
    const int half = (base >= HALF) ? 256 : 0;   // block-uniform (scalar)

    // Stage this block's codebook half: 256 lanes x 16 B = 4 KB, one instruction.
    lut[threadIdx.x] = codebooks[half + threadIdx.x];
    __syncthreads();

    int   code[GPT];
    float s[GPT];

    // Batch the streaming loads first: 8 independent chains in flight.
    #pragma unroll
    for (int k = 0; k < GPT; ++k) {
        const int g = base + k * BLOCK + threadIdx.x;
        code[k] = __builtin_nontemporal_load(&codes[g]);   // read-once stream
        s[k]    = __builtin_nontemporal_load(&scales[g >> 4]);
    }

    #pragma unroll
    for (int k = 0; k < GPT; ++k) {
        const int g = base + k * BLOCK + threadIdx.x;
        f32x4 c = lut[code[k]];                            // ds_read_b128 gather
        c *= s[k];
        __builtin_nontemporal_store(c, &out[g]);           // write-once stream
    }
}

extern "C" void kernel_launch(void* const* d_in, const int* in_sizes, int n_in,
                              void* d_out, int out_size, void* d_ws, size_t ws_size,
                              hipStream_t stream) {
    const f32x4* codebooks = (const f32x4*)d_in[0];
    const float* scales    = (const float*)d_in[1];
    const int*   codes     = (const int*)d_in[2];
    f32x4*       out       = (f32x4*)d_out;

    dequant_kernel<<<N_GROUPS / GROUPS_PER_BLOCK, BLOCK, 0, stream>>>(
        codebooks, scales, codes, out);
}